// Round 1
// baseline (3223.202 us; speedup 1.0000x reference)
//
#include <hip/hip_runtime.h>
#include <math.h>

constexpr int B_ = 2, N_ = 1024, D_ = 384, H_ = 8, HD_ = 48, DFF2 = 512, L_ = 4;
constexpr int BN_ = B_ * N_;                       // 2048 rows
constexpr size_t NNs = (size_t)N_ * N_;            // 1048576
constexpr size_t BNNc = (size_t)B_ * N_ * N_;      // 2097152
constexpr int QR = 8, JT = 64;
constexpr float RSCALE = 0.14433756729740643f;     // 1/sqrt(48)

__device__ inline float wsum(float v) {
#pragma unroll
  for (int m = 32; m; m >>= 1) v += __shfl_xor(v, m, 64);
  return v;
}

// ---------------------------------------------------------------- copy
__global__ __launch_bounds__(256) void copy_kernel(float* __restrict__ dst,
                                                   const float* __restrict__ src, int n) {
  int i = blockIdx.x * 256 + threadIdx.x;
  if (i < n) dst[i] = src[i];
}

// ---------------------------------------------------------------- layernorm (wave per row)
__global__ __launch_bounds__(256) void ln_kernel(const float* __restrict__ x,
                                                 const float* __restrict__ g,
                                                 const float* __restrict__ b,
                                                 float* __restrict__ out) {
  int lane = threadIdx.x & 63, wid = threadIdx.x >> 6;
  int row = blockIdx.x * 4 + wid;
  const float* xp = x + (size_t)row * D_;
  float v[6], s = 0.f, s2 = 0.f;
#pragma unroll
  for (int i = 0; i < 6; ++i) {
    v[i] = xp[lane + i * 64];
    s += v[i]; s2 += v[i] * v[i];
  }
  s = wsum(s); s2 = wsum(s2);
  float mean = s * (1.0f / D_);
  float var = s2 * (1.0f / D_) - mean * mean;
  float rstd = rsqrtf(var + 1e-5f);
  float* op = out + (size_t)row * D_;
#pragma unroll
  for (int i = 0; i < 6; ++i) {
    int d = lane + i * 64;
    op[d] = (v[i] - mean) * rstd * g[d] + b[d];
  }
}

// ---------------------------------------------------------------- v3d = h @ W3 + b3 (wave per row)
__global__ __launch_bounds__(256) void v3d_kernel(const float* __restrict__ h,
                                                  const float* __restrict__ W3,
                                                  const float* __restrict__ b3,
                                                  float* __restrict__ v3d) {
  int lane = threadIdx.x & 63, wid = threadIdx.x >> 6;
  int row = blockIdx.x * 4 + wid;
  const float* hp = h + (size_t)row * D_;
  float a0 = 0.f, a1 = 0.f, a2 = 0.f;
  for (int k = lane; k < D_; k += 64) {
    float hv = hp[k];
    a0 += hv * W3[k * 3 + 0];
    a1 += hv * W3[k * 3 + 1];
    a2 += hv * W3[k * 3 + 2];
  }
  a0 = wsum(a0); a1 = wsum(a1); a2 = wsum(a2);
  if (lane == 0) {
    v3d[row * 3 + 0] = a0 + b3[0];
    v3d[row * 3 + 1] = a1 + b3[1];
    v3d[row * 3 + 2] = a2 + b3[2];
  }
}

// ---------------------------------------------------------------- tiled fp32 GEMM  C[M,Nc] = A[M,K] @ W[K,Nc] + bias
// EPI: 0=store, 1=residual add into C, 2=relu store, 3=transposed store (kT/vT [B,D,N] layout)
template <int EPI>
__global__ __launch_bounds__(256) void gemm_kernel(const float* __restrict__ A, int lda,
                                                   const float* __restrict__ W, int ldb,
                                                   const float* __restrict__ bias,
                                                   float* __restrict__ C, int ldc, int K) {
  __shared__ __align__(16) float As[16][68];
  __shared__ __align__(16) float Bs[16][68];
  int tid = threadIdx.x;
  int tx = tid & 15, ty = tid >> 4;
  int row0 = blockIdx.y * 64, col0 = blockIdx.x * 64;
  float acc[4][4] = {};
  for (int kt = 0; kt < K; kt += 16) {
#pragma unroll
    for (int i = 0; i < 4; ++i) {
      int e = tid + i * 256, m = e >> 4, k = e & 15;
      int kg = kt + k;
      As[k][m] = (kg < K) ? A[(size_t)(row0 + m) * lda + kg] : 0.f;
    }
#pragma unroll
    for (int i = 0; i < 4; ++i) {
      int e = tid + i * 256, k = e >> 6, n = e & 63;
      int kg = kt + k;
      Bs[k][n] = (kg < K) ? W[(size_t)kg * ldb + col0 + n] : 0.f;
    }
    __syncthreads();
#pragma unroll
    for (int k = 0; k < 16; ++k) {
      float av[4], bv[4];
#pragma unroll
      for (int i = 0; i < 4; ++i) av[i] = As[k][ty * 4 + i];
#pragma unroll
      for (int j = 0; j < 4; ++j) bv[j] = Bs[k][tx * 4 + j];
#pragma unroll
      for (int i = 0; i < 4; ++i)
#pragma unroll
        for (int j = 0; j < 4; ++j) acc[i][j] += av[i] * bv[j];
    }
    __syncthreads();
  }
#pragma unroll
  for (int i = 0; i < 4; ++i) {
    int row = row0 + ty * 4 + i;
#pragma unroll
    for (int j = 0; j < 4; ++j) {
      int col = col0 + tx * 4 + j;
      float v = acc[i][j] + bias[col];
      if (EPI == 0) C[(size_t)row * ldc + col] = v;
      if (EPI == 1) C[(size_t)row * ldc + col] += v;
      if (EPI == 2) C[(size_t)row * ldc + col] = fmaxf(v, 0.f);
      if (EPI == 3) C[((size_t)(row >> 10) * D_ + col) * N_ + (row & 1023)] = v;
    }
  }
}

// ---------------------------------------------------------------- fused attention + merged softmax + frame
// One block = 8 query rows, all 8 heads. Online softmax per (row,head) AND per row for
// the head-summed ("merged") scores; frame = mean_j merged * cross(ad, colsum(ori)*v3d[j]).
__global__ __launch_bounds__(256) void attn_kernel(const float* __restrict__ q,
                                                   const float* __restrict__ kT,
                                                   const float* __restrict__ vT,
                                                   const float* __restrict__ dist,
                                                   const int* __restrict__ mask,
                                                   const float* __restrict__ ad,
                                                   const float* __restrict__ ori,
                                                   const float* __restrict__ v3d,
                                                   const float* __restrict__ Wmlp_l,
                                                   const float* __restrict__ bmlp_l,
                                                   float* __restrict__ concat) {
  __shared__ __align__(16) float qs[QR][D_];          // 12 KB
  __shared__ __align__(16) float oacc[QR][D_ + 4];    // 12.1 KB (pad: stride 388 -> 4 banks apart per r)
  __shared__ float ss[QR * 516];                      // scores/probs [r][j'][h], row stride 516
  __shared__ float ssum[QR][JT];                      // head-summed scores / merged probs
  __shared__ float v3s[JT][3];
  __shared__ float mh[QR][H_], lh[QR][H_], fh[QR][H_];
  __shared__ float mg[QR], lg[QR], fg[QR];
  __shared__ float fracc[QR][3];
  __shared__ float wm[16];
  __shared__ float bm_s;

  const int t = threadIdx.x;
  const int i0 = blockIdx.x * QR;
  const int b = i0 >> 10;
  const int ib = i0 & 1023;

  for (int idx = t; idx < QR * D_; idx += 256) ((float*)qs)[idx] = q[(size_t)i0 * D_ + idx];
  for (int idx = t; idx < QR * (D_ + 4); idx += 256) ((float*)oacc)[idx] = 0.f;
  if (t < QR * H_) { ((float*)mh)[t] = -INFINITY; ((float*)lh)[t] = 0.f; }
  if (t < QR) { mg[t] = -INFINITY; lg[t] = 0.f; }
  if (t < QR * 3) ((float*)fracc)[t] = 0.f;
  if (t < 16) wm[t] = Wmlp_l[t];
  if (t == 16) bm_s = bmlp_l[0];
  __syncthreads();

  const int jp = t & 63;
  const int g = t >> 6;

  for (int jt = 0; jt < N_; jt += JT) {
    // ---------- Phase A: scores for all heads ----------
    if (g == 0) {
      const float* vp = v3d + (size_t)(b * N_ + jt + jp) * 3;
      v3s[jp][0] = vp[0]; v3s[jp][1] = vp[1]; v3s[jp][2] = vp[2];
    }
    float disv[QR];
    int mkv[QR];
    {
      size_t base = (size_t)b * NNs + (size_t)ib * N_ + jt + jp;
#pragma unroll
      for (int r = 0; r < QR; ++r) {
        float dv = dist[base + (size_t)r * N_];
        mkv[r] = mask[base + (size_t)r * N_];
        float s = bm_s;
#pragma unroll
        for (int rr = 0; rr < 16; ++rr) {
          float tt = (dv - (float)rr * (20.0f / 15.0f)) * 0.8f;  // /sigma=1.25
          s += __expf(-tt * tt) * wm[rr];
        }
        disv[r] = s;
      }
    }
    for (int hh = 0; hh < 2; ++hh) {
      int h = g + hh * 4;
      float acc[QR] = {};
      const float* kp = kT + ((size_t)b * D_ + h * HD_) * N_ + jt + jp;
      for (int dq = 0; dq < HD_ / 4; ++dq) {
        float kv0 = kp[(size_t)(dq * 4 + 0) * N_];
        float kv1 = kp[(size_t)(dq * 4 + 1) * N_];
        float kv2 = kp[(size_t)(dq * 4 + 2) * N_];
        float kv3 = kp[(size_t)(dq * 4 + 3) * N_];
#pragma unroll
        for (int r = 0; r < QR; ++r) {
          const float4 q4 = *reinterpret_cast<const float4*>(&qs[r][h * HD_ + dq * 4]);
          acc[r] += q4.x * kv0 + q4.y * kv1 + q4.z * kv2 + q4.w * kv3;
        }
      }
#pragma unroll
      for (int r = 0; r < QR; ++r) {
        float s = (mkv[r] == 0) ? -1e9f : acc[r] * RSCALE + disv[r];
        ss[r * 516 + jp * 8 + h] = s;
      }
    }
    __syncthreads();
    // ---------- Phase A2: head-sum ----------
    for (int r = g; r < QR; r += 4) {
      float s = 0.f;
#pragma unroll
      for (int h = 0; h < H_; ++h) s += ss[r * 516 + jp * 8 + h];
      ssum[r][jp] = s;
    }
    __syncthreads();
    // ---------- Phase B: online softmax updates ----------
    if (t < 64) {
      int r = t >> 3, h = t & 7;
      float m0 = mh[r][h], tm = -INFINITY;
      for (int j = 0; j < JT; ++j) tm = fmaxf(tm, ss[r * 516 + j * 8 + h]);
      float nm = fmaxf(m0, tm);
      float f = __expf(m0 - nm);
      float l = lh[r][h] * f;
      for (int j = 0; j < JT; ++j) {
        float p = __expf(ss[r * 516 + j * 8 + h] - nm);
        ss[r * 516 + j * 8 + h] = p;
        l += p;
      }
      mh[r][h] = nm; lh[r][h] = l; fh[r][h] = f;
    } else if (t < 72) {
      int r = t - 64;
      float m0 = mg[r], tm = -INFINITY;
      for (int j = 0; j < JT; ++j) tm = fmaxf(tm, ssum[r][j]);
      float nm = fmaxf(m0, tm);
      float f = __expf(m0 - nm);
      float l = lg[r] * f;
      for (int j = 0; j < JT; ++j) {
        float p = __expf(ssum[r][j] - nm);
        ssum[r][j] = p;
        l += p;
      }
      mg[r] = nm; lg[r] = l; fg[r] = f;
    }
    __syncthreads();
    // ---------- Phase C: PV accumulate (d-major mapping keeps vT reads line-efficient) ----------
    for (int idx = t; idx < QR * D_; idx += 256) {
      int r = idx & 7, d = idx >> 3;
      int h = d / HD_;
      float o = oacc[r][d] * fh[r][h];
      const float4* vp4 = reinterpret_cast<const float4*>(vT + ((size_t)b * D_ + d) * N_ + jt);
      const float* sp = &ss[r * 516 + h];
#pragma unroll
      for (int jq = 0; jq < JT / 4; ++jq) {
        float4 v4 = vp4[jq];
        o += sp[(jq * 4 + 0) * 8] * v4.x;
        o += sp[(jq * 4 + 1) * 8] * v4.y;
        o += sp[(jq * 4 + 2) * 8] * v4.z;
        o += sp[(jq * 4 + 3) * 8] * v4.w;
      }
      oacc[r][d] = o;
    }
    // ---------- frame accumulate (merged-softmax weighted geometric term) ----------
    for (int r = g; r < QR; r += 4) {
      float pgv = ssum[r][jp];
      size_t pij = ((size_t)b * N_ + (size_t)(ib + r)) * N_ + jt + jp;
      const float* op = ori + pij * 9;
      const float* ap = ad + pij * 3;
      float a0 = ap[0], a1 = ap[1], a2 = ap[2];
      float u0 = (op[0] + op[3] + op[6]) * v3s[jp][0];
      float u1 = (op[1] + op[4] + op[7]) * v3s[jp][1];
      float u2 = (op[2] + op[5] + op[8]) * v3s[jp][2];
      float d0 = wsum((a1 * u2 - a2 * u1) * pgv);
      float d1 = wsum((a2 * u0 - a0 * u2) * pgv);
      float d2 = wsum((a0 * u1 - a1 * u0) * pgv);
      if (jp == 0) {
        float ff = fg[r];
        fracc[r][0] = fracc[r][0] * ff + d0;
        fracc[r][1] = fracc[r][1] * ff + d1;
        fracc[r][2] = fracc[r][2] * ff + d2;
      }
    }
    __syncthreads();
  }
  // ---------- finalize: write concat[attn_v | frame] ----------
  for (int idx = t; idx < QR * D_; idx += 256) {
    int r = idx & 7, d = idx >> 3;
    concat[(size_t)(i0 + r) * 387 + d] = oacc[r][d] / lh[r][d / HD_];
  }
  if (t < QR * 3) {
    int r = t / 3, c = t % 3;
    concat[(size_t)(i0 + r) * 387 + 384 + c] = fracc[r][c] / lg[r] * (1.0f / N_);
  }
}

// ---------------------------------------------------------------- launch
extern "C" void kernel_launch(void* const* d_in, const int* in_sizes, int n_in,
                              void* d_out, int out_size, void* d_ws, size_t ws_size,
                              hipStream_t stream) {
  const float* x_rigid = (const float*)d_in[0];
  const float* ad      = (const float*)d_in[1];
  const float* ori     = (const float*)d_in[2];
  const float* dist    = (const float*)d_in[3];
  const int*   mask    = (const int*)d_in[4];
  const float* Wq  = (const float*)d_in[5];
  const float* bq  = (const float*)d_in[6];
  const float* Wk  = (const float*)d_in[7];
  const float* bk  = (const float*)d_in[8];
  const float* Wv  = (const float*)d_in[9];
  const float* bv  = (const float*)d_in[10];
  const float* W3  = (const float*)d_in[11];
  const float* b3  = (const float*)d_in[12];
  const float* Wmlp = (const float*)d_in[13];
  const float* bmlp = (const float*)d_in[14];
  const float* Wfc  = (const float*)d_in[15];
  const float* bfc  = (const float*)d_in[16];
  const float* Wff1 = (const float*)d_in[17];
  const float* bff1 = (const float*)d_in[18];
  const float* Wff2 = (const float*)d_in[19];
  const float* bff2 = (const float*)d_in[20];
  const float* ln1g = (const float*)d_in[21];
  const float* ln1b = (const float*)d_in[22];
  const float* ln2g = (const float*)d_in[23];
  const float* ln2b = (const float*)d_in[24];

  float* x = (float*)d_out;
  float* p = (float*)d_ws;
  float* kT = p; p += (size_t)BN_ * D_;
  float* vT = p; p += (size_t)BN_ * D_;
  float* qb = p; p += (size_t)BN_ * D_;
  float* hb = p; p += (size_t)BN_ * D_;
  float* h2 = p; p += (size_t)BN_ * D_;
  float* v3 = p; p += (size_t)BN_ * 3;
  float* cc = p; p += (size_t)BN_ * 387;
  float* ff = p; p += (size_t)BN_ * DFF2;
  size_t need = (size_t)(p - (float*)d_ws) * sizeof(float);
  if (ws_size < need) return;  // insufficient scratch — fail loudly via poisoned output

  copy_kernel<<<(BN_ * D_) / 256, 256, 0, stream>>>(x, x_rigid, BN_ * D_);

  dim3 g384(6, 32), g512(8, 32);
  for (int l = 0; l < L_; ++l) {
    ln_kernel<<<BN_ / 4, 256, 0, stream>>>(x, ln1g + l * D_, ln1b + l * D_, hb);
    gemm_kernel<0><<<g384, 256, 0, stream>>>(hb, D_, Wq + (size_t)l * D_ * D_, D_, bq + l * D_, qb, D_, D_);
    gemm_kernel<3><<<g384, 256, 0, stream>>>(hb, D_, Wk + (size_t)l * D_ * D_, D_, bk + l * D_, kT, D_, D_);
    gemm_kernel<3><<<g384, 256, 0, stream>>>(hb, D_, Wv + (size_t)l * D_ * D_, D_, bv + l * D_, vT, D_, D_);
    v3d_kernel<<<BN_ / 4, 256, 0, stream>>>(hb, W3 + (size_t)l * D_ * 3, b3 + l * 3, v3);
    attn_kernel<<<BN_ / QR, 256, 0, stream>>>(qb, kT, vT, dist, mask, ad, ori, v3,
                                              Wmlp + l * 16, bmlp + l, cc);
    gemm_kernel<1><<<g384, 256, 0, stream>>>(cc, 387, Wfc + (size_t)l * 387 * D_, D_, bfc + l * D_, x, D_, 387);
    ln_kernel<<<BN_ / 4, 256, 0, stream>>>(x, ln2g + l * D_, ln2b + l * D_, h2);
    gemm_kernel<2><<<g512, 256, 0, stream>>>(h2, D_, Wff1 + (size_t)l * D_ * DFF2, DFF2, bff1 + l * DFF2, ff, DFF2, D_);
    gemm_kernel<1><<<g384, 256, 0, stream>>>(ff, DFF2, Wff2 + (size_t)l * DFF2 * D_, D_, bff2 + l * D_, x, D_, DFF2);
  }
}

// Round 2
// 1038.356 us; speedup vs baseline: 3.1041x; 3.1041x over previous
//
#include <hip/hip_runtime.h>
#include <math.h>

constexpr int B_ = 2, N_ = 1024, D_ = 384, H_ = 8, HD_ = 48, DFF2 = 512, L_ = 4;
constexpr int BN_ = B_ * N_;                       // 2048 rows
constexpr size_t NNs = (size_t)N_ * N_;            // 1048576
constexpr size_t BNNc = (size_t)B_ * N_ * N_;      // 2097152
constexpr int QR = 8, JT = 64, NSPLIT = 4;
constexpr int CCLD = 416;                          // cc row stride (387 padded to 13*32)
constexpr float RSCALE = 0.14433756729740643f;     // 1/sqrt(48)

typedef short bf16x8 __attribute__((ext_vector_type(8)));
typedef float f32x4 __attribute__((ext_vector_type(4)));

__device__ inline float wsum(float v) {
#pragma unroll
  for (int m = 32; m; m >>= 1) v += __shfl_xor(v, m, 64);
  return v;
}
__device__ inline float b2f(unsigned short s) {
  union { unsigned int u; float f; } v; v.u = ((unsigned int)s) << 16; return v.f;
}
__device__ inline unsigned short f2b(float f) {
  union { float f; unsigned int u; } v; v.f = f;
  unsigned int r = v.u + 0x7fffu + ((v.u >> 16) & 1u);
  return (unsigned short)(r >> 16);
}

// ---------------------------------------------------------------- copy
__global__ __launch_bounds__(256) void copy_kernel(float* __restrict__ dst,
                                                   const float* __restrict__ src, int n) {
  int i = blockIdx.x * 256 + threadIdx.x;
  if (i < n) dst[i] = src[i];
}

// ---------------------------------------------------------------- weight packing (fp32 -> bf16 transposed)
__global__ __launch_bounds__(256) void pack_qkv_kernel(const float* __restrict__ Wq,
                                                       const float* __restrict__ Wk,
                                                       const float* __restrict__ Wv,
                                                       unsigned short* __restrict__ out) {
  int idx = blockIdx.x * 256 + threadIdx.x;
  if (idx >= L_ * 1152 * D_) return;
  int l = idx / (1152 * D_);
  int r = idx % (1152 * D_);
  int n = r / D_, k = r % D_;
  float v;
  if (n < 384)      v = Wq[((size_t)l * D_ + k) * D_ + n];
  else if (n < 768) v = Wk[((size_t)l * D_ + k) * D_ + (n - 384)];
  else              v = Wv[((size_t)l * D_ + k) * D_ + (n - 768)];
  out[idx] = f2b(v);
}
__global__ __launch_bounds__(256) void pack_bias_kernel(const float* __restrict__ bq,
                                                        const float* __restrict__ bk,
                                                        const float* __restrict__ bv,
                                                        float* __restrict__ out) {
  int idx = blockIdx.x * 256 + threadIdx.x;
  if (idx >= L_ * 1152) return;
  int l = idx / 1152, n = idx % 1152;
  out[idx] = (n < 384) ? bq[l * D_ + n] : (n < 768) ? bk[l * D_ + n - 384] : bv[l * D_ + n - 768];
}
__global__ __launch_bounds__(256) void pack_fc_kernel(const float* __restrict__ Wfc,
                                                      unsigned short* __restrict__ out) {
  int idx = blockIdx.x * 256 + threadIdx.x;
  if (idx >= L_ * D_ * CCLD) return;
  int l = idx / (D_ * CCLD);
  int r = idx % (D_ * CCLD);
  int n = r / CCLD, k = r % CCLD;
  float v = (k < 387) ? Wfc[((size_t)l * 387 + k) * D_ + n] : 0.f;
  out[idx] = f2b(v);
}
__global__ __launch_bounds__(256) void pack_ff1_kernel(const float* __restrict__ W,
                                                       unsigned short* __restrict__ out) {
  int idx = blockIdx.x * 256 + threadIdx.x;
  if (idx >= L_ * DFF2 * D_) return;
  int l = idx / (DFF2 * D_);
  int r = idx % (DFF2 * D_);
  int n = r / D_, k = r % D_;
  out[idx] = f2b(W[((size_t)l * D_ + k) * DFF2 + n]);
}
__global__ __launch_bounds__(256) void pack_ff2_kernel(const float* __restrict__ W,
                                                       unsigned short* __restrict__ out) {
  int idx = blockIdx.x * 256 + threadIdx.x;
  if (idx >= L_ * D_ * DFF2) return;
  int l = idx / (D_ * DFF2);
  int r = idx % (D_ * DFF2);
  int n = r / DFF2, k = r % DFF2;
  out[idx] = f2b(W[((size_t)l * DFF2 + k) * D_ + n]);
}

// ---------------------------------------------------------------- geometry precompute (layer-independent)
// G[p][0..5] = (a1*c2, a2*c1, a2*c0, a0*c2, a0*c1, a1*c0); c = colsum(orientation), a = altered_direction
__global__ __launch_bounds__(256) void geom_kernel(const float* __restrict__ ori,
                                                   const float* __restrict__ ad,
                                                   float* __restrict__ G) {
  size_t i = (size_t)blockIdx.x * 256 + threadIdx.x;
  size_t stride = (size_t)gridDim.x * 256;
  for (; i < BNNc; i += stride) {
    const float* op = ori + i * 9;
    const float* ap = ad + i * 3;
    float c0 = op[0] + op[3] + op[6];
    float c1 = op[1] + op[4] + op[7];
    float c2 = op[2] + op[5] + op[8];
    float a0 = ap[0], a1 = ap[1], a2 = ap[2];
    float* gp = G + i * 6;
    gp[0] = a1 * c2; gp[1] = a2 * c1; gp[2] = a2 * c0;
    gp[3] = a0 * c2; gp[4] = a0 * c1; gp[5] = a1 * c0;
  }
}

// ---------------------------------------------------------------- per-layer RBF distance bias (+mask fold)
__global__ __launch_bounds__(256) void rbf_kernel(const float* __restrict__ dist,
                                                  const int* __restrict__ mask,
                                                  const float* __restrict__ wm,
                                                  const float* __restrict__ bm,
                                                  float* __restrict__ dbias) {
  size_t i = (size_t)blockIdx.x * 256 + threadIdx.x;
  size_t stride = (size_t)gridDim.x * 256;
  float w[16];
#pragma unroll
  for (int r = 0; r < 16; ++r) w[r] = wm[r];
  float b0 = bm[0];
  for (; i < BNNc; i += stride) {
    float dv = dist[i];
    float sv = b0;
#pragma unroll
    for (int r = 0; r < 16; ++r) {
      float tt = (dv - (float)r * (20.0f / 15.0f)) * 0.8f;  // mu=linspace(0,20,16), 1/sigma=0.8
      sv += __expf(-tt * tt) * w[r];
    }
    dbias[i] = (mask[i] == 0) ? -1e9f : sv;
  }
}

// ---------------------------------------------------------------- layernorm (wave per row, bf16 out)
__global__ __launch_bounds__(256) void ln_kernel(const float* __restrict__ x,
                                                 const float* __restrict__ g,
                                                 const float* __restrict__ b,
                                                 unsigned short* __restrict__ out) {
  int lane = threadIdx.x & 63, wid = threadIdx.x >> 6;
  int row = blockIdx.x * 4 + wid;
  const float* xp = x + (size_t)row * D_;
  float v[6], s = 0.f, s2 = 0.f;
#pragma unroll
  for (int i = 0; i < 6; ++i) {
    v[i] = xp[lane + i * 64];
    s += v[i]; s2 += v[i] * v[i];
  }
  s = wsum(s); s2 = wsum(s2);
  float mean = s * (1.0f / D_);
  float var = s2 * (1.0f / D_) - mean * mean;
  float rstd = rsqrtf(var + 1e-5f);
  unsigned short* op = out + (size_t)row * D_;
#pragma unroll
  for (int i = 0; i < 6; ++i) {
    int d = lane + i * 64;
    op[d] = f2b((v[i] - mean) * rstd * g[d] + b[d]);
  }
}

// ---------------------------------------------------------------- v3d = h @ W3 + b3 (wave per row, bf16 in)
__global__ __launch_bounds__(256) void v3d_kernel(const unsigned short* __restrict__ h,
                                                  const float* __restrict__ W3,
                                                  const float* __restrict__ b3,
                                                  float* __restrict__ v3d) {
  int lane = threadIdx.x & 63, wid = threadIdx.x >> 6;
  int row = blockIdx.x * 4 + wid;
  const unsigned short* hp = h + (size_t)row * D_;
  float a0 = 0.f, a1 = 0.f, a2 = 0.f;
  for (int k = lane; k < D_; k += 64) {
    float hv = b2f(hp[k]);
    a0 += hv * W3[k * 3 + 0];
    a1 += hv * W3[k * 3 + 1];
    a2 += hv * W3[k * 3 + 2];
  }
  a0 = wsum(a0); a1 = wsum(a1); a2 = wsum(a2);
  if (lane == 0) {
    v3d[row * 3 + 0] = a0 + b3[0];
    v3d[row * 3 + 1] = a1 + b3[1];
    v3d[row * 3 + 2] = a2 + b3[2];
  }
}

// ---------------------------------------------------------------- bf16 MFMA GEMM, C = A @ W^T(packed) + bias
// BM in {32,64}; BN=64. EPI: 0 = qkv (split store q plain, k/v transposed), 1 = fp32 += (residual),
// 2 = relu -> bf16 store.
template <int BM, int EPI>
__global__ __launch_bounds__(256) void mfma_gemm(const unsigned short* __restrict__ A, int lda,
                                                 const unsigned short* __restrict__ WT, int ldw,
                                                 const float* __restrict__ bias,
                                                 float* __restrict__ C0, float* __restrict__ C1,
                                                 float* __restrict__ C2, int ldc, int K) {
  constexpr int MI = BM / 32;  // 16x16 m-tiles per wave
  int t = threadIdx.x;
  int l = t & 63, w = t >> 6;
  int lr = l & 15, lk = l >> 4;
  int n0 = blockIdx.x * 64 + (w >> 1) * 32;
  int m0 = blockIdx.y * BM + (w & 1) * (BM / 2);
  f32x4 acc[MI][2] = {};
  const unsigned short* pa[MI];
  const unsigned short* pb[2];
#pragma unroll
  for (int mi = 0; mi < MI; ++mi) pa[mi] = A + (size_t)(m0 + mi * 16 + lr) * lda + lk * 8;
#pragma unroll
  for (int ni = 0; ni < 2; ++ni) pb[ni] = WT + (size_t)(n0 + ni * 16 + lr) * ldw + lk * 8;
#pragma unroll 4
  for (int kt = 0; kt < K; kt += 32) {
    bf16x8 av[MI], bv[2];
#pragma unroll
    for (int mi = 0; mi < MI; ++mi) av[mi] = *reinterpret_cast<const bf16x8*>(pa[mi] + kt);
#pragma unroll
    for (int ni = 0; ni < 2; ++ni) bv[ni] = *reinterpret_cast<const bf16x8*>(pb[ni] + kt);
#pragma unroll
    for (int mi = 0; mi < MI; ++mi)
#pragma unroll
      for (int ni = 0; ni < 2; ++ni)
        acc[mi][ni] = __builtin_amdgcn_mfma_f32_16x16x32_bf16(av[mi], bv[ni], acc[mi][ni], 0, 0, 0);
  }
#pragma unroll
  for (int mi = 0; mi < MI; ++mi)
#pragma unroll
    for (int ni = 0; ni < 2; ++ni)
#pragma unroll
      for (int e = 0; e < 4; ++e) {
        int row = m0 + mi * 16 + lk * 4 + e;
        int col = n0 + ni * 16 + lr;
        float v = acc[mi][ni][e] + bias[col];
        if (EPI == 0) {
          if (col < 384)      C0[(size_t)row * ldc + col] = v;
          else if (col < 768) C1[(((size_t)(row >> 10)) * D_ + (col - 384)) * N_ + (row & 1023)] = v;
          else                C2[(((size_t)(row >> 10)) * D_ + (col - 768)) * N_ + (row & 1023)] = v;
        }
        if (EPI == 1) C0[(size_t)row * ldc + col] += v;
        if (EPI == 2) ((unsigned short*)C0)[(size_t)row * ldc + col] = f2b(fmaxf(v, 0.f));
      }
}

// ---------------------------------------------------------------- fused attention, j-split partials
// Block = 8 q-rows x all heads x 1/NSPLIT of j. Per-head + merged online softmax; frame from G.
template <bool USEG>
__global__ __launch_bounds__(256) void attn_kernel(
    const float* __restrict__ q, const float* __restrict__ kT, const float* __restrict__ vT,
    const float* __restrict__ dbias, const float* __restrict__ G,
    const float* __restrict__ ad, const float* __restrict__ ori,
    const float* __restrict__ v3d,
    float* __restrict__ pO, float* __restrict__ pM, float* __restrict__ pL,
    float* __restrict__ pF, float* __restrict__ pMg, float* __restrict__ pLg) {
  __shared__ __align__(16) float qs[QR][D_];         // 12 KB
  __shared__ __align__(16) float oacc[QR][D_ + 4];   // 12.1 KB
  __shared__ __align__(16) float ss[H_ * QR * 68];   // scores/probs [h][r][j], stride 68 -> <=2-way
  __shared__ float ssum[QR * 68];
  __shared__ float v3s[JT][3];
  __shared__ float mh[QR][H_], lh[QR][H_], fh[QR][H_];
  __shared__ float mg[QR], lg[QR], fg[QR];
  __shared__ float fracc[QR][3];

  const int t = threadIdx.x;
  const int s = blockIdx.y;
  const int i0 = blockIdx.x * QR;
  const int b = i0 >> 10;
  const int ib = i0 & 1023;
  const int jp = t & 63;
  const int g = t >> 6;

  for (int idx = t; idx < QR * D_; idx += 256) ((float*)qs)[idx] = q[(size_t)i0 * D_ + idx];
  for (int idx = t; idx < QR * (D_ + 4); idx += 256) ((float*)oacc)[idx] = 0.f;
  if (t < QR * H_) { ((float*)mh)[t] = -INFINITY; ((float*)lh)[t] = 0.f; }
  if (t < QR) { mg[t] = -INFINITY; lg[t] = 0.f; }
  if (t < QR * 3) ((float*)fracc)[t] = 0.f;
  __syncthreads();

  for (int jt = s * (N_ / NSPLIT); jt < (s + 1) * (N_ / NSPLIT); jt += JT) {
    // ---------- Phase A: raw scores (qk/scale + dbias), all heads ----------
    if (g == 0) {
      const float* vp = v3d + (size_t)(b * N_ + jt + jp) * 3;
      v3s[jp][0] = vp[0]; v3s[jp][1] = vp[1]; v3s[jp][2] = vp[2];
    }
    float disv[QR];
    {
      size_t base = (size_t)b * NNs + (size_t)ib * N_ + jt + jp;
#pragma unroll
      for (int r = 0; r < QR; ++r) disv[r] = dbias[base + (size_t)r * N_];
    }
#pragma unroll
    for (int hh = 0; hh < 2; ++hh) {
      int h = g + hh * 4;
      float acc[QR] = {};
      const float* kp = kT + ((size_t)b * D_ + h * HD_) * N_ + jt + jp;
#pragma unroll
      for (int dq = 0; dq < HD_ / 4; ++dq) {
        float kv0 = kp[(size_t)(dq * 4 + 0) * N_];
        float kv1 = kp[(size_t)(dq * 4 + 1) * N_];
        float kv2 = kp[(size_t)(dq * 4 + 2) * N_];
        float kv3 = kp[(size_t)(dq * 4 + 3) * N_];
#pragma unroll
        for (int r = 0; r < QR; ++r) {
          const float4 q4 = *reinterpret_cast<const float4*>(&qs[r][h * HD_ + dq * 4]);
          acc[r] += q4.x * kv0 + q4.y * kv1 + q4.z * kv2 + q4.w * kv3;
        }
      }
#pragma unroll
      for (int r = 0; r < QR; ++r) ss[(h * QR + r) * 68 + jp] = acc[r] * RSCALE + disv[r];
    }
    __syncthreads();
    // ---------- Phase A2: head-sum for merged softmax ----------
    for (int r = g; r < QR; r += 4) {
      float sum = 0.f;
#pragma unroll
      for (int h = 0; h < H_; ++h) sum += ss[(h * QR + r) * 68 + jp];
      ssum[r * 68 + jp] = sum;
    }
    __syncthreads();
    // ---------- Phase B: online softmax, 4 threads per (h,r) ----------
    {
      int p = t >> 2, c = t & 3;
      int h = p >> 3, r = p & 7;
      float* sp = &ss[(h * QR + r) * 68 + c * 16];
      float tm = -INFINITY;
#pragma unroll
      for (int j = 0; j < 16; ++j) tm = fmaxf(tm, sp[j]);
      tm = fmaxf(tm, __shfl_xor(tm, 1, 64));
      tm = fmaxf(tm, __shfl_xor(tm, 2, 64));
      float m0 = mh[r][h];
      float nm = fmaxf(m0, tm);
      float lsum = 0.f;
#pragma unroll
      for (int j = 0; j < 16; ++j) { float pv = __expf(sp[j] - nm); sp[j] = pv; lsum += pv; }
      lsum += __shfl_xor(lsum, 1, 64);
      lsum += __shfl_xor(lsum, 2, 64);
      if (c == 0) {
        float f = __expf(m0 - nm);
        mh[r][h] = nm; lh[r][h] = lh[r][h] * f + lsum; fh[r][h] = f;
      }
    }
    if (t < QR * 4) {
      int r = t >> 2, c = t & 3;
      float* sp = &ssum[r * 68 + c * 16];
      float tm = -INFINITY;
#pragma unroll
      for (int j = 0; j < 16; ++j) tm = fmaxf(tm, sp[j]);
      tm = fmaxf(tm, __shfl_xor(tm, 1, 64));
      tm = fmaxf(tm, __shfl_xor(tm, 2, 64));
      float m0 = mg[r];
      float nm = fmaxf(m0, tm);
      float lsum = 0.f;
#pragma unroll
      for (int j = 0; j < 16; ++j) { float pv = __expf(sp[j] - nm); sp[j] = pv; lsum += pv; }
      lsum += __shfl_xor(lsum, 1, 64);
      lsum += __shfl_xor(lsum, 2, 64);
      if (c == 0) {
        float f = __expf(m0 - nm);
        mg[r] = nm; lg[r] = lg[r] * f + lsum; fg[r] = f;
      }
    }
    __syncthreads();
    // ---------- Phase C: PV accumulate (d-outer: v4 reused across all 8 rows) ----------
    for (int d = t; d < D_; d += 256) {
      int h = d / HD_;
      const float4* vp4 = reinterpret_cast<const float4*>(vT + ((size_t)b * D_ + d) * N_ + jt);
      float o[QR];
#pragma unroll
      for (int r = 0; r < QR; ++r) o[r] = oacc[r][d] * fh[r][h];
#pragma unroll
      for (int jq = 0; jq < JT / 4; ++jq) {
        float4 v4 = vp4[jq];
#pragma unroll
        for (int r = 0; r < QR; ++r) {
          float4 p4 = *reinterpret_cast<const float4*>(&ss[(h * QR + r) * 68 + jq * 4]);
          o[r] += p4.x * v4.x + p4.y * v4.y + p4.z * v4.z + p4.w * v4.w;
        }
      }
#pragma unroll
      for (int r = 0; r < QR; ++r) oacc[r][d] = o[r];
    }
    // ---------- frame accumulate ----------
    for (int r = g; r < QR; r += 4) {
      float pgv = ssum[r * 68 + jp];
      size_t pij = ((size_t)b * N_ + (size_t)(ib + r)) * N_ + jt + jp;
      float w0 = v3s[jp][0], w1 = v3s[jp][1], w2 = v3s[jp][2];
      float d0, d1, d2;
      if (USEG) {
        const float* gp = G + pij * 6;
        d0 = gp[0] * w2 - gp[1] * w1;
        d1 = gp[2] * w0 - gp[3] * w2;
        d2 = gp[4] * w1 - gp[5] * w0;
      } else {
        const float* op = ori + pij * 9;
        const float* ap = ad + pij * 3;
        float a0 = ap[0], a1 = ap[1], a2 = ap[2];
        float u0 = (op[0] + op[3] + op[6]) * w0;
        float u1 = (op[1] + op[4] + op[7]) * w1;
        float u2 = (op[2] + op[5] + op[8]) * w2;
        d0 = a1 * u2 - a2 * u1; d1 = a2 * u0 - a0 * u2; d2 = a0 * u1 - a1 * u0;
      }
      d0 = wsum(d0 * pgv); d1 = wsum(d1 * pgv); d2 = wsum(d2 * pgv);
      if (jp == 0) {
        float ffc = fg[r];
        fracc[r][0] = fracc[r][0] * ffc + d0;
        fracc[r][1] = fracc[r][1] * ffc + d1;
        fracc[r][2] = fracc[r][2] * ffc + d2;
      }
    }
    __syncthreads();
  }
  // ---------- write split partials ----------
  {
    size_t rowb = (size_t)s * BN_ + i0;
    for (int idx = t; idx < QR * D_; idx += 256) {
      int r = idx & 7, d = idx >> 3;
      pO[(rowb + r) * D_ + d] = oacc[r][d];
    }
    if (t < QR * H_) {
      int r = t >> 3, h = t & 7;
      pM[(rowb + r) * H_ + h] = mh[r][h];
      pL[(rowb + r) * H_ + h] = lh[r][h];
    }
    if (t < QR * 3) {
      int r = t / 3, c = t % 3;
      pF[(rowb + r) * 3 + c] = fracc[r][c];
    }
    if (t < QR) { pMg[rowb + t] = mg[t]; pLg[rowb + t] = lg[t]; }
  }
}

// ---------------------------------------------------------------- combine split partials -> cc (bf16, padded)
__global__ __launch_bounds__(256) void combine_kernel(
    const float* __restrict__ pO, const float* __restrict__ pM, const float* __restrict__ pL,
    const float* __restrict__ pF, const float* __restrict__ pMg, const float* __restrict__ pLg,
    unsigned short* __restrict__ cc) {
  __shared__ float sc[QR][H_][NSPLIT];
  __shared__ float scg[QR][NSPLIT];
  int t = threadIdx.x;
  int i0 = blockIdx.x * QR;
  if (t < QR * H_) {
    int r = t >> 3, h = t & 7;
    size_t row = i0 + r;
    float ms[NSPLIT], ls[NSPLIT], m = -INFINITY;
#pragma unroll
    for (int s2 = 0; s2 < NSPLIT; ++s2) {
      ms[s2] = pM[((size_t)s2 * BN_ + row) * H_ + h];
      ls[s2] = pL[((size_t)s2 * BN_ + row) * H_ + h];
      m = fmaxf(m, ms[s2]);
    }
    float L = 0.f, e[NSPLIT];
#pragma unroll
    for (int s2 = 0; s2 < NSPLIT; ++s2) { e[s2] = __expf(ms[s2] - m); L += ls[s2] * e[s2]; }
    float invL = 1.0f / L;
#pragma unroll
    for (int s2 = 0; s2 < NSPLIT; ++s2) sc[r][h][s2] = e[s2] * invL;
  } else if (t < QR * H_ + QR) {
    int r = t - QR * H_;
    size_t row = i0 + r;
    float ms[NSPLIT], ls[NSPLIT], m = -INFINITY;
#pragma unroll
    for (int s2 = 0; s2 < NSPLIT; ++s2) {
      ms[s2] = pMg[(size_t)s2 * BN_ + row];
      ls[s2] = pLg[(size_t)s2 * BN_ + row];
      m = fmaxf(m, ms[s2]);
    }
    float L = 0.f, e[NSPLIT];
#pragma unroll
    for (int s2 = 0; s2 < NSPLIT; ++s2) { e[s2] = __expf(ms[s2] - m); L += ls[s2] * e[s2]; }
    float inv = 1.0f / (L * (float)N_);
#pragma unroll
    for (int s2 = 0; s2 < NSPLIT; ++s2) scg[r][s2] = e[s2] * inv;
  }
  __syncthreads();
  for (int idx = t; idx < QR * D_; idx += 256) {
    int r = idx & 7, d = idx >> 3;
    size_t row = i0 + r;
    int h = d / HD_;
    float o = 0.f;
#pragma unroll
    for (int s2 = 0; s2 < NSPLIT; ++s2) o += pO[((size_t)s2 * BN_ + row) * D_ + d] * sc[r][h][s2];
    cc[row * CCLD + d] = f2b(o);
  }
  if (t < QR * 3) {
    int r = t / 3, c = t % 3;
    size_t row = i0 + r;
    float F = 0.f;
#pragma unroll
    for (int s2 = 0; s2 < NSPLIT; ++s2) F += pF[((size_t)s2 * BN_ + row) * 3 + c] * scg[r][s2];
    cc[row * CCLD + 384 + c] = f2b(F);
  }
  for (int idx = t; idx < QR * (CCLD - 387); idx += 256) {
    int r = idx / (CCLD - 387), col = 387 + idx % (CCLD - 387);
    cc[(size_t)(i0 + r) * CCLD + col] = 0;
  }
}

// ---------------------------------------------------------------- launch
extern "C" void kernel_launch(void* const* d_in, const int* in_sizes, int n_in,
                              void* d_out, int out_size, void* d_ws, size_t ws_size,
                              hipStream_t stream) {
  const float* x_rigid = (const float*)d_in[0];
  const float* ad      = (const float*)d_in[1];
  const float* ori     = (const float*)d_in[2];
  const float* dist    = (const float*)d_in[3];
  const int*   mask    = (const int*)d_in[4];
  const float* Wq  = (const float*)d_in[5];
  const float* bq  = (const float*)d_in[6];
  const float* Wk  = (const float*)d_in[7];
  const float* bk  = (const float*)d_in[8];
  const float* Wv  = (const float*)d_in[9];
  const float* bv  = (const float*)d_in[10];
  const float* W3  = (const float*)d_in[11];
  const float* b3  = (const float*)d_in[12];
  const float* Wmlp = (const float*)d_in[13];
  const float* bmlp = (const float*)d_in[14];
  const float* Wfc  = (const float*)d_in[15];
  const float* bfc  = (const float*)d_in[16];
  const float* Wff1 = (const float*)d_in[17];
  const float* bff1 = (const float*)d_in[18];
  const float* Wff2 = (const float*)d_in[19];
  const float* bff2 = (const float*)d_in[20];
  const float* ln1g = (const float*)d_in[21];
  const float* ln1b = (const float*)d_in[22];
  const float* ln2g = (const float*)d_in[23];
  const float* ln2b = (const float*)d_in[24];

  float* x = (float*)d_out;

  size_t off = 0;
  auto alloc = [&](size_t bytes) -> void* {
    void* r = (char*)d_ws + off;
    off = (off + bytes + 255) & ~(size_t)255;
    return r;
  };
  unsigned short* WqkvT = (unsigned short*)alloc((size_t)L_ * 1152 * D_ * 2);
  unsigned short* WfcT  = (unsigned short*)alloc((size_t)L_ * D_ * CCLD * 2);
  unsigned short* Wff1T = (unsigned short*)alloc((size_t)L_ * DFF2 * D_ * 2);
  unsigned short* Wff2T = (unsigned short*)alloc((size_t)L_ * D_ * DFF2 * 2);
  float* bqkv = (float*)alloc((size_t)L_ * 1152 * 4);
  float* dbias = (float*)alloc(BNNc * 4);
  float* qb = (float*)alloc((size_t)BN_ * D_ * 4);
  float* kT = (float*)alloc((size_t)BN_ * D_ * 4);
  float* vT = (float*)alloc((size_t)BN_ * D_ * 4);
  unsigned short* hb = (unsigned short*)alloc((size_t)BN_ * D_ * 2);
  unsigned short* h2 = (unsigned short*)alloc((size_t)BN_ * D_ * 2);
  unsigned short* cc = (unsigned short*)alloc((size_t)BN_ * CCLD * 2);
  unsigned short* ffb = (unsigned short*)alloc((size_t)BN_ * DFF2 * 2);
  float* v3 = (float*)alloc((size_t)BN_ * 3 * 4);
  float* pO = (float*)alloc((size_t)NSPLIT * BN_ * D_ * 4);
  float* pM = (float*)alloc((size_t)NSPLIT * BN_ * H_ * 4);
  float* pL = (float*)alloc((size_t)NSPLIT * BN_ * H_ * 4);
  float* pF = (float*)alloc((size_t)NSPLIT * BN_ * 3 * 4);
  float* pMg = (float*)alloc((size_t)NSPLIT * BN_ * 4);
  float* pLg = (float*)alloc((size_t)NSPLIT * BN_ * 4);
  size_t need_base = off;
  float* G = (float*)alloc(BNNc * 6 * 4);
  bool useG = (off <= ws_size);
  if (ws_size < need_base) return;  // insufficient scratch

  // one-time packs / precomputes (run every call; cheap)
  pack_qkv_kernel<<<(L_ * 1152 * D_ + 255) / 256, 256, 0, stream>>>(Wq, Wk, Wv, WqkvT);
  pack_bias_kernel<<<(L_ * 1152 + 255) / 256, 256, 0, stream>>>(bq, bk, bv, bqkv);
  pack_fc_kernel<<<(L_ * D_ * CCLD + 255) / 256, 256, 0, stream>>>(Wfc, WfcT);
  pack_ff1_kernel<<<(L_ * DFF2 * D_ + 255) / 256, 256, 0, stream>>>(Wff1, Wff1T);
  pack_ff2_kernel<<<(L_ * D_ * DFF2 + 255) / 256, 256, 0, stream>>>(Wff2, Wff2T);
  if (useG) geom_kernel<<<4096, 256, 0, stream>>>(ori, ad, G);
  copy_kernel<<<(BN_ * D_) / 256, 256, 0, stream>>>(x, x_rigid, BN_ * D_);

  for (int l = 0; l < L_; ++l) {
    rbf_kernel<<<4096, 256, 0, stream>>>(dist, mask, Wmlp + l * 16, bmlp + l, dbias);
    ln_kernel<<<BN_ / 4, 256, 0, stream>>>(x, ln1g + l * D_, ln1b + l * D_, hb);
    mfma_gemm<64, 0><<<dim3(18, 32), 256, 0, stream>>>(
        hb, D_, WqkvT + (size_t)l * 1152 * D_, D_, bqkv + l * 1152, qb, kT, vT, D_, D_);
    v3d_kernel<<<BN_ / 4, 256, 0, stream>>>(hb, W3 + (size_t)l * D_ * 3, b3 + l * 3, v3);
    if (useG)
      attn_kernel<true><<<dim3(BN_ / QR, NSPLIT), 256, 0, stream>>>(
          qb, kT, vT, dbias, G, ad, ori, v3, pO, pM, pL, pF, pMg, pLg);
    else
      attn_kernel<false><<<dim3(BN_ / QR, NSPLIT), 256, 0, stream>>>(
          qb, kT, vT, dbias, G, ad, ori, v3, pO, pM, pL, pF, pMg, pLg);
    combine_kernel<<<BN_ / QR, 256, 0, stream>>>(pO, pM, pL, pF, pMg, pLg, cc);
    mfma_gemm<32, 1><<<dim3(6, 64), 256, 0, stream>>>(
        cc, CCLD, WfcT + (size_t)l * D_ * CCLD, CCLD, bfc + l * D_, x, nullptr, nullptr, D_, CCLD);
    ln_kernel<<<BN_ / 4, 256, 0, stream>>>(x, ln2g + l * D_, ln2b + l * D_, h2);
    mfma_gemm<64, 2><<<dim3(8, 32), 256, 0, stream>>>(
        h2, D_, Wff1T + (size_t)l * DFF2 * D_, D_, bff1 + l * DFF2, (float*)ffb, nullptr, nullptr,
        DFF2, D_);
    mfma_gemm<32, 1><<<dim3(6, 64), 256, 0, stream>>>(
        ffb, DFF2, Wff2T + (size_t)l * D_ * DFF2, DFF2, bff2 + l * D_, x, nullptr, nullptr, D_,
        DFF2);
  }
}

// Round 3
// 550.645 us; speedup vs baseline: 5.8535x; 1.8857x over previous
//
#include <hip/hip_runtime.h>
#include <math.h>

constexpr int B_ = 2, N_ = 1024, D_ = 384, H_ = 8, HD_ = 48, DFF2 = 512, L_ = 4;
constexpr int BN_ = B_ * N_;                       // 2048 rows
constexpr size_t NNs = (size_t)N_ * N_;            // 1048576
constexpr size_t BNNc = (size_t)B_ * N_ * N_;      // 2097152
constexpr int JT = 64, NSPLIT = 4;
constexpr int CCLD = 416;                          // cc row stride (387 padded)
constexpr float RSCALE = 0.14433756729740643f;     // 1/sqrt(48)

typedef short bf16x8 __attribute__((ext_vector_type(8)));
typedef float f32x4 __attribute__((ext_vector_type(4)));

__device__ inline float wsum(float v) {
#pragma unroll
  for (int m = 32; m; m >>= 1) v += __shfl_xor(v, m, 64);
  return v;
}
__device__ inline float b2f(unsigned short s) {
  union { unsigned int u; float f; } v; v.u = ((unsigned int)s) << 16; return v.f;
}
__device__ inline unsigned short f2b(float f) {
  union { float f; unsigned int u; } v; v.f = f;
  unsigned int r = v.u + 0x7fffu + ((v.u >> 16) & 1u);
  return (unsigned short)(r >> 16);
}

// ---------------------------------------------------------------- copy / zero
__global__ __launch_bounds__(256) void copy_kernel(float* __restrict__ dst,
                                                   const float* __restrict__ src, int n) {
  int i = blockIdx.x * 256 + threadIdx.x;
  if (i < n) dst[i] = src[i];
}
__global__ __launch_bounds__(256) void zero_kernel(unsigned int* __restrict__ p, int n) {
  int i = blockIdx.x * 256 + threadIdx.x;
  if (i < n) p[i] = 0u;
}

// ---------------------------------------------------------------- weight packing (fp32 -> bf16 transposed)
__global__ __launch_bounds__(256) void pack_qkv_kernel(const float* __restrict__ Wq,
                                                       const float* __restrict__ Wk,
                                                       const float* __restrict__ Wv,
                                                       unsigned short* __restrict__ out) {
  int idx = blockIdx.x * 256 + threadIdx.x;
  if (idx >= L_ * 1152 * D_) return;
  int l = idx / (1152 * D_);
  int r = idx % (1152 * D_);
  int n = r / D_, k = r % D_;
  float v;
  if (n < 384)      v = Wq[((size_t)l * D_ + k) * D_ + n];
  else if (n < 768) v = Wk[((size_t)l * D_ + k) * D_ + (n - 384)];
  else              v = Wv[((size_t)l * D_ + k) * D_ + (n - 768)];
  out[idx] = f2b(v);
}
__global__ __launch_bounds__(256) void pack_bias_kernel(const float* __restrict__ bq,
                                                        const float* __restrict__ bk,
                                                        const float* __restrict__ bv,
                                                        float* __restrict__ out) {
  int idx = blockIdx.x * 256 + threadIdx.x;
  if (idx >= L_ * 1152) return;
  int l = idx / 1152, n = idx % 1152;
  out[idx] = (n < 384) ? bq[l * D_ + n] : (n < 768) ? bk[l * D_ + n - 384] : bv[l * D_ + n - 768];
}
__global__ __launch_bounds__(256) void pack_fc_kernel(const float* __restrict__ Wfc,
                                                      unsigned short* __restrict__ out) {
  int idx = blockIdx.x * 256 + threadIdx.x;
  if (idx >= L_ * D_ * CCLD) return;
  int l = idx / (D_ * CCLD);
  int r = idx % (D_ * CCLD);
  int n = r / CCLD, k = r % CCLD;
  float v = (k < 387) ? Wfc[((size_t)l * 387 + k) * D_ + n] : 0.f;
  out[idx] = f2b(v);
}
__global__ __launch_bounds__(256) void pack_ff1_kernel(const float* __restrict__ W,
                                                       unsigned short* __restrict__ out) {
  int idx = blockIdx.x * 256 + threadIdx.x;
  if (idx >= L_ * DFF2 * D_) return;
  int l = idx / (DFF2 * D_);
  int r = idx % (DFF2 * D_);
  int n = r / D_, k = r % D_;
  out[idx] = f2b(W[((size_t)l * D_ + k) * DFF2 + n]);
}
__global__ __launch_bounds__(256) void pack_ff2_kernel(const float* __restrict__ W,
                                                       unsigned short* __restrict__ out) {
  int idx = blockIdx.x * 256 + threadIdx.x;
  if (idx >= L_ * D_ * DFF2) return;
  int l = idx / (D_ * DFF2);
  int r = idx % (D_ * DFF2);
  int n = r / DFF2, k = r % DFF2;
  out[idx] = f2b(W[((size_t)l * DFF2 + k) * D_ + n]);
}

// ---------------------------------------------------------------- geometry precompute (layer-independent)
__global__ __launch_bounds__(256) void geom_kernel(const float* __restrict__ ori,
                                                   const float* __restrict__ ad,
                                                   float* __restrict__ G) {
  size_t i = (size_t)blockIdx.x * 256 + threadIdx.x;
  size_t stride = (size_t)gridDim.x * 256;
  for (; i < BNNc; i += stride) {
    const float* op = ori + i * 9;
    const float* ap = ad + i * 3;
    float c0 = op[0] + op[3] + op[6];
    float c1 = op[1] + op[4] + op[7];
    float c2 = op[2] + op[5] + op[8];
    float a0 = ap[0], a1 = ap[1], a2 = ap[2];
    float* gp = G + i * 6;
    gp[0] = a1 * c2; gp[1] = a2 * c1; gp[2] = a2 * c0;
    gp[3] = a0 * c2; gp[4] = a0 * c1; gp[5] = a1 * c0;
  }
}

// ---------------------------------------------------------------- RBF bias: all 4 layers in one pass
__global__ __launch_bounds__(256) void rbf4_kernel(const float* __restrict__ dist,
                                                   const int* __restrict__ mask,
                                                   const float* __restrict__ Wmlp,
                                                   const float* __restrict__ bmlp,
                                                   float* __restrict__ db4) {
  size_t i = (size_t)blockIdx.x * 256 + threadIdx.x;
  size_t stride = (size_t)gridDim.x * 256;
  for (; i < BNNc; i += stride) {
    float dv = dist[i];
    bool msk = (mask[i] == 0);
    float rb[16];
#pragma unroll
    for (int r = 0; r < 16; ++r) {
      float tt = (dv - (float)r * (20.0f / 15.0f)) * 0.8f;
      rb[r] = __expf(-tt * tt);
    }
#pragma unroll
    for (int l2 = 0; l2 < L_; ++l2) {
      float sv = bmlp[l2];
#pragma unroll
      for (int r = 0; r < 16; ++r) sv += rb[r] * Wmlp[l2 * 16 + r];
      db4[(size_t)l2 * BNNc + i] = msk ? -1e9f : sv;
    }
  }
}
// per-layer fallback (small workspace)
__global__ __launch_bounds__(256) void rbf_kernel(const float* __restrict__ dist,
                                                  const int* __restrict__ mask,
                                                  const float* __restrict__ wm,
                                                  const float* __restrict__ bm,
                                                  float* __restrict__ dbias) {
  size_t i = (size_t)blockIdx.x * 256 + threadIdx.x;
  size_t stride = (size_t)gridDim.x * 256;
  float w[16];
#pragma unroll
  for (int r = 0; r < 16; ++r) w[r] = wm[r];
  float b0 = bm[0];
  for (; i < BNNc; i += stride) {
    float dv = dist[i];
    float sv = b0;
#pragma unroll
    for (int r = 0; r < 16; ++r) {
      float tt = (dv - (float)r * (20.0f / 15.0f)) * 0.8f;
      sv += __expf(-tt * tt) * w[r];
    }
    dbias[i] = (mask[i] == 0) ? -1e9f : sv;
  }
}

// ---------------------------------------------------------------- layernorm (wave per row, bf16 out)
__global__ __launch_bounds__(256) void ln_kernel(const float* __restrict__ x,
                                                 const float* __restrict__ g,
                                                 const float* __restrict__ b,
                                                 unsigned short* __restrict__ out) {
  int lane = threadIdx.x & 63, wid = threadIdx.x >> 6;
  int row = blockIdx.x * 4 + wid;
  const float* xp = x + (size_t)row * D_;
  float v[6], s = 0.f, s2 = 0.f;
#pragma unroll
  for (int i = 0; i < 6; ++i) {
    v[i] = xp[lane + i * 64];
    s += v[i]; s2 += v[i] * v[i];
  }
  s = wsum(s); s2 = wsum(s2);
  float mean = s * (1.0f / D_);
  float var = s2 * (1.0f / D_) - mean * mean;
  float rstd = rsqrtf(var + 1e-5f);
  unsigned short* op = out + (size_t)row * D_;
#pragma unroll
  for (int i = 0; i < 6; ++i) {
    int d = lane + i * 64;
    op[d] = f2b((v[i] - mean) * rstd * g[d] + b[d]);
  }
}

// ---------------------------------------------------------------- v3d = h @ W3 + b3 (wave per row, bf16 in)
__global__ __launch_bounds__(256) void v3d_kernel(const unsigned short* __restrict__ h,
                                                  const float* __restrict__ W3,
                                                  const float* __restrict__ b3,
                                                  float* __restrict__ v3d) {
  int lane = threadIdx.x & 63, wid = threadIdx.x >> 6;
  int row = blockIdx.x * 4 + wid;
  const unsigned short* hp = h + (size_t)row * D_;
  float a0 = 0.f, a1 = 0.f, a2 = 0.f;
  for (int k = lane; k < D_; k += 64) {
    float hv = b2f(hp[k]);
    a0 += hv * W3[k * 3 + 0];
    a1 += hv * W3[k * 3 + 1];
    a2 += hv * W3[k * 3 + 2];
  }
  a0 = wsum(a0); a1 = wsum(a1); a2 = wsum(a2);
  if (lane == 0) {
    v3d[row * 3 + 0] = a0 + b3[0];
    v3d[row * 3 + 1] = a1 + b3[1];
    v3d[row * 3 + 2] = a2 + b3[2];
  }
}

// ---------------------------------------------------------------- bf16 MFMA GEMM  C = A @ WT + bias
// EPI 0: qkv -> q/k bf16 [B,N,H,64] padded (RSCALE on q), v -> bf16 vT [B,D,N]
// EPI 1: fp32 += (residual)   EPI 2: relu -> bf16
template <int BM, int EPI>
__global__ __launch_bounds__(256) void mfma_gemm(const unsigned short* __restrict__ A, int lda,
                                                 const unsigned short* __restrict__ WT, int ldw,
                                                 const float* __restrict__ bias,
                                                 float* __restrict__ C0, float* __restrict__ C1,
                                                 float* __restrict__ C2, int ldc, int K) {
  constexpr int MI = BM / 32;
  int t = threadIdx.x;
  int l = t & 63, w = t >> 6;
  int lr = l & 15, lk = l >> 4;
  int n0 = blockIdx.x * 64 + (w >> 1) * 32;
  int m0 = blockIdx.y * BM + (w & 1) * (BM / 2);
  f32x4 acc[MI][2] = {};
  const unsigned short* pa[MI];
  const unsigned short* pb2[2];
#pragma unroll
  for (int mi = 0; mi < MI; ++mi) pa[mi] = A + (size_t)(m0 + mi * 16 + lr) * lda + lk * 8;
#pragma unroll
  for (int ni = 0; ni < 2; ++ni) pb2[ni] = WT + (size_t)(n0 + ni * 16 + lr) * ldw + lk * 8;
#pragma unroll 4
  for (int kt = 0; kt < K; kt += 32) {
    bf16x8 av[MI], bv[2];
#pragma unroll
    for (int mi = 0; mi < MI; ++mi) av[mi] = *reinterpret_cast<const bf16x8*>(pa[mi] + kt);
#pragma unroll
    for (int ni = 0; ni < 2; ++ni) bv[ni] = *reinterpret_cast<const bf16x8*>(pb2[ni] + kt);
#pragma unroll
    for (int mi = 0; mi < MI; ++mi)
#pragma unroll
      for (int ni = 0; ni < 2; ++ni)
        acc[mi][ni] = __builtin_amdgcn_mfma_f32_16x16x32_bf16(av[mi], bv[ni], acc[mi][ni], 0, 0, 0);
  }
#pragma unroll
  for (int mi = 0; mi < MI; ++mi)
#pragma unroll
    for (int ni = 0; ni < 2; ++ni)
#pragma unroll
      for (int e = 0; e < 4; ++e) {
        int row = m0 + mi * 16 + lk * 4 + e;
        int col = n0 + ni * 16 + lr;
        float v = acc[mi][ni][e] + bias[col];
        if (EPI == 0) {
          if (col < 384) {
            int h = col / 48, hd = col - h * 48;
            ((unsigned short*)C0)[(size_t)row * 512 + h * 64 + hd] = f2b(v * RSCALE);
          } else if (col < 768) {
            int c2 = col - 384;
            int h = c2 / 48, hd = c2 - h * 48;
            ((unsigned short*)C1)[(size_t)row * 512 + h * 64 + hd] = f2b(v);
          } else {
            int c2 = col - 768;
            ((unsigned short*)C2)[((size_t)(row >> 10) * D_ + c2) * N_ + (row & 1023)] = f2b(v);
          }
        }
        if (EPI == 1) C0[(size_t)row * ldc + col] += v;
        if (EPI == 2) ((unsigned short*)C0)[(size_t)row * ldc + col] = f2b(fmaxf(v, 0.f));
      }
}

// ---------------------------------------------------------------- MFMA fused attention (16 rows, 4 waves)
// wave wv owns heads {wv, wv+4}. Per j-tile: QK^T MFMA -> LDS scores; per-head softmax
// (2 thr/(h,r), j-strided) -> bf16 P in LDS; merged softmax (16 thr/row) from raw LDS scores;
// PV MFMA with register O-frags; frame term with per-lane register partials.
template <bool USEG>
__global__ __launch_bounds__(256) void attn16_kernel(
    const unsigned short* __restrict__ qp, const unsigned short* __restrict__ kp,
    const unsigned short* __restrict__ vTb, const float* __restrict__ db_l,
    const float* __restrict__ G, const float* __restrict__ ad, const float* __restrict__ ori,
    const float* __restrict__ v3d,
    float* __restrict__ pO, float* __restrict__ pM, float* __restrict__ pL,
    float* __restrict__ pF, float* __restrict__ pMg, float* __restrict__ pLg) {
  __shared__ __align__(16) float ss[8 * 16 * 70];        // raw scores [h][r][70]
  __shared__ __align__(16) unsigned int pbuf[8 * 16 * 36]; // P bf16 pairs [h][r][36]
  __shared__ __align__(16) float dbs[16 * 70];            // dbias tile
  __shared__ __align__(16) float msum[16 * 70];           // merged probs
  __shared__ __align__(16) float fh_s[8 * 16];
  __shared__ float fg_s[16];

  const int t = threadIdx.x;
  const int wv = t >> 6, l = t & 63;
  const int lr = l & 15, lk = l >> 4;
  const int sgrp = blockIdx.y;
  const int i0 = blockIdx.x * 16;
  const int b = i0 >> 10, ib = i0 & 1023;

  // persistent Q fragments (RSCALE prefolded at pack time)
  bf16x8 qf[2][2];
#pragma unroll
  for (int hp = 0; hp < 2; ++hp) {
    int h = wv + hp * 4;
#pragma unroll
    for (int ks = 0; ks < 2; ++ks)
      qf[hp][ks] = *reinterpret_cast<const bf16x8*>(
          qp + (size_t)(i0 + lr) * 512 + h * 64 + ks * 32 + lk * 8);
  }
  f32x4 Ofr[2][3] = {};
  float fracc[4][3] = {};
  const int sh = t >> 5, sr = (t >> 1) & 15, sc_ = t & 1;  // per-head softmax role
  const int mr = t >> 4, mc = t & 15;                       // merged softmax role
  float m_ph = -INFINITY, l_ph = 0.f, m_mg = -INFINITY, l_mg = 0.f;

  for (int jt = sgrp * (N_ / NSPLIT); jt < (sgrp + 1) * (N_ / NSPLIT); jt += JT) {
    // ---- Phase 1: stage dbias tile + QK^T MFMA ----
#pragma unroll
    for (int u = 0; u < 4; ++u) {
      int idx = t + u * 256, r = idx >> 6, j = idx & 63;
      dbs[r * 70 + j] = db_l[(size_t)b * NNs + (size_t)(ib + r) * N_ + jt + j];
    }
#pragma unroll
    for (int hp = 0; hp < 2; ++hp) {
      int h = wv + hp * 4;
      bf16x8 kf0[4], kf1[4];
#pragma unroll
      for (int nj = 0; nj < 4; ++nj) {
        const unsigned short* kb = kp + (size_t)(jt + nj * 16 + lr) * 512 + h * 64 + lk * 8;
        kf0[nj] = *reinterpret_cast<const bf16x8*>(kb);
        kf1[nj] = *reinterpret_cast<const bf16x8*>(kb + 32);
      }
#pragma unroll
      for (int nj = 0; nj < 4; ++nj) {
        f32x4 acc = {};
        acc = __builtin_amdgcn_mfma_f32_16x16x32_bf16(qf[hp][0], kf0[nj], acc, 0, 0, 0);
        acc = __builtin_amdgcn_mfma_f32_16x16x32_bf16(qf[hp][1], kf1[nj], acc, 0, 0, 0);
#pragma unroll
        for (int e = 0; e < 4; ++e)
          ss[h * 1120 + (lk * 4 + e) * 70 + nj * 16 + lr] = acc[e];
      }
    }
    __syncthreads();
    // ---- Phase 2a: per-head online softmax, P -> bf16 LDS ----
    {
      float sv[32];
      float tmax = -INFINITY;
      const int base = sh * 1120 + sr * 70 + sc_;
      const int dbase = sr * 70 + sc_;
#pragma unroll
      for (int i = 0; i < 32; ++i) {
        sv[i] = ss[base + 2 * i] + dbs[dbase + 2 * i];
        tmax = fmaxf(tmax, sv[i]);
      }
      tmax = fmaxf(tmax, __shfl_xor(tmax, 1, 64));
      float nm = fmaxf(m_ph, tmax);
      float f = __expf(m_ph - nm);
      m_ph = nm;
      float lsum = 0.f;
#pragma unroll
      for (int i = 0; i < 32; ++i) { sv[i] = __expf(sv[i] - nm); lsum += sv[i]; }
      lsum += __shfl_xor(lsum, 1, 64);
      l_ph = l_ph * f + lsum;
      if (sc_ == 0) fh_s[sh * 16 + sr] = f;
      const int prow = (sh * 16 + sr) * 36;
#pragma unroll
      for (int i = 0; i < 32; ++i) {
        float other = __shfl_xor(sv[i], 1, 64);
        if ((i < 16) == (sc_ == 0)) {
          float ev = (sc_ == 0) ? sv[i] : other;
          float od = (sc_ == 0) ? other : sv[i];
          pbuf[prow + i] = ((unsigned int)f2b(od) << 16) | (unsigned int)f2b(ev);
        }
      }
    }
    // ---- Phase 2b: merged softmax (reads raw ss over all heads) ----
    {
      float mv[4];
      float tmax = -INFINITY;
#pragma unroll
      for (int i = 0; i < 4; ++i) {
        int j = mc + 16 * i;
        float v = 8.f * dbs[mr * 70 + j];
#pragma unroll
        for (int h = 0; h < 8; ++h) v += ss[h * 1120 + mr * 70 + j];
        mv[i] = v;
        tmax = fmaxf(tmax, v);
      }
#pragma unroll
      for (int m2 = 1; m2 < 16; m2 <<= 1) tmax = fmaxf(tmax, __shfl_xor(tmax, m2, 64));
      float nm = fmaxf(m_mg, tmax);
      float f = __expf(m_mg - nm);
      m_mg = nm;
      float lsum = 0.f;
#pragma unroll
      for (int i = 0; i < 4; ++i) {
        mv[i] = __expf(mv[i] - nm);
        lsum += mv[i];
        msum[mr * 70 + mc + 16 * i] = mv[i];
      }
#pragma unroll
      for (int m2 = 1; m2 < 16; m2 <<= 1) lsum += __shfl_xor(lsum, m2, 64);
      l_mg = l_mg * f + lsum;
      if (mc == 0) fg_s[mr] = f;
    }
    __syncthreads();
    // ---- Phase 3: PV MFMA + frame accumulate ----
#pragma unroll
    for (int hp = 0; hp < 2; ++hp) {
      int h = wv + hp * 4;
      f32x4 fv = *reinterpret_cast<const f32x4*>(&fh_s[h * 16 + lk * 4]);
      bf16x8 af0 = *reinterpret_cast<const bf16x8*>(&pbuf[(h * 16 + lr) * 36 + lk * 4]);
      bf16x8 af1 = *reinterpret_cast<const bf16x8*>(&pbuf[(h * 16 + lr) * 36 + 16 + lk * 4]);
#pragma unroll
      for (int ni = 0; ni < 3; ++ni) {
        const unsigned short* vb =
            vTb + (size_t)(b * D_ + h * 48 + ni * 16 + lr) * N_ + jt + lk * 8;
        bf16x8 bf0 = *reinterpret_cast<const bf16x8*>(vb);
        bf16x8 bf1 = *reinterpret_cast<const bf16x8*>(vb + 32);
        f32x4 o = Ofr[hp][ni];
#pragma unroll
        for (int e = 0; e < 4; ++e) o[e] *= fv[e];
        o = __builtin_amdgcn_mfma_f32_16x16x32_bf16(af0, bf0, o, 0, 0, 0);
        o = __builtin_amdgcn_mfma_f32_16x16x32_bf16(af1, bf1, o, 0, 0, 0);
        Ofr[hp][ni] = o;
      }
    }
    {
      const float* vp = v3d + (size_t)((b << 10) + jt + l) * 3;
      float w0 = vp[0], w1 = vp[1], w2 = vp[2];
#pragma unroll
      for (int e = 0; e < 4; ++e) {
        int r = wv * 4 + e;
        float pm = msum[r * 70 + l];
        size_t pij = ((size_t)b * N_ + (ib + r)) * N_ + jt + l;
        float d0, d1, d2;
        if (USEG) {
          const float* gp = G + pij * 6;
          d0 = gp[0] * w2 - gp[1] * w1;
          d1 = gp[2] * w0 - gp[3] * w2;
          d2 = gp[4] * w1 - gp[5] * w0;
        } else {
          const float* op = ori + pij * 9;
          const float* ap = ad + pij * 3;
          float a0 = ap[0], a1 = ap[1], a2 = ap[2];
          float u0 = (op[0] + op[3] + op[6]) * w0;
          float u1 = (op[1] + op[4] + op[7]) * w1;
          float u2 = (op[2] + op[5] + op[8]) * w2;
          d0 = a1 * u2 - a2 * u1; d1 = a2 * u0 - a0 * u2; d2 = a0 * u1 - a1 * u0;
        }
        float fgr = fg_s[r];
        fracc[e][0] = fracc[e][0] * fgr + pm * d0;
        fracc[e][1] = fracc[e][1] * fgr + pm * d1;
        fracc[e][2] = fracc[e][2] * fgr + pm * d2;
      }
    }
    __syncthreads();
  }
  // ---- epilogue: write split partials ----
  const size_t rowb = (size_t)sgrp * BN_ + i0;
#pragma unroll
  for (int hp = 0; hp < 2; ++hp)
#pragma unroll
    for (int ni = 0; ni < 3; ++ni)
#pragma unroll
      for (int e = 0; e < 4; ++e)
        pO[(rowb + lk * 4 + e) * D_ + (wv + hp * 4) * 48 + ni * 16 + lr] = Ofr[hp][ni][e];
#pragma unroll
  for (int e = 0; e < 4; ++e)
#pragma unroll
    for (int c = 0; c < 3; ++c) {
      float v = wsum(fracc[e][c]);
      if (l == 0) pF[(rowb + wv * 4 + e) * 3 + c] = v;
    }
  if (sc_ == 0) {
    pM[(rowb + sr) * H_ + sh] = m_ph;
    pL[(rowb + sr) * H_ + sh] = l_ph;
  }
  if (mc == 0) { pMg[rowb + mr] = m_mg; pLg[rowb + mr] = l_mg; }
}

// ---------------------------------------------------------------- combine split partials -> cc (bf16, padded)
constexpr int QR = 8;
__global__ __launch_bounds__(256) void combine_kernel(
    const float* __restrict__ pO, const float* __restrict__ pM, const float* __restrict__ pL,
    const float* __restrict__ pF, const float* __restrict__ pMg, const float* __restrict__ pLg,
    unsigned short* __restrict__ cc) {
  __shared__ float sc[QR][H_][NSPLIT];
  __shared__ float scg[QR][NSPLIT];
  int t = threadIdx.x;
  int i0 = blockIdx.x * QR;
  if (t < QR * H_) {
    int r = t >> 3, h = t & 7;
    size_t row = i0 + r;
    float ms[NSPLIT], ls[NSPLIT], m = -INFINITY;
#pragma unroll
    for (int s2 = 0; s2 < NSPLIT; ++s2) {
      ms[s2] = pM[((size_t)s2 * BN_ + row) * H_ + h];
      ls[s2] = pL[((size_t)s2 * BN_ + row) * H_ + h];
      m = fmaxf(m, ms[s2]);
    }
    float L = 0.f, e[NSPLIT];
#pragma unroll
    for (int s2 = 0; s2 < NSPLIT; ++s2) { e[s2] = __expf(ms[s2] - m); L += ls[s2] * e[s2]; }
    float invL = 1.0f / L;
#pragma unroll
    for (int s2 = 0; s2 < NSPLIT; ++s2) sc[r][h][s2] = e[s2] * invL;
  } else if (t < QR * H_ + QR) {
    int r = t - QR * H_;
    size_t row = i0 + r;
    float ms[NSPLIT], ls[NSPLIT], m = -INFINITY;
#pragma unroll
    for (int s2 = 0; s2 < NSPLIT; ++s2) {
      ms[s2] = pMg[(size_t)s2 * BN_ + row];
      ls[s2] = pLg[(size_t)s2 * BN_ + row];
      m = fmaxf(m, ms[s2]);
    }
    float L = 0.f, e[NSPLIT];
#pragma unroll
    for (int s2 = 0; s2 < NSPLIT; ++s2) { e[s2] = __expf(ms[s2] - m); L += ls[s2] * e[s2]; }
    float inv = 1.0f / (L * (float)N_);
#pragma unroll
    for (int s2 = 0; s2 < NSPLIT; ++s2) scg[r][s2] = e[s2] * inv;
  }
  __syncthreads();
  for (int idx = t; idx < QR * D_; idx += 256) {
    int r = idx & 7, d = idx >> 3;
    size_t row = i0 + r;
    int h = d / HD_;
    float o = 0.f;
#pragma unroll
    for (int s2 = 0; s2 < NSPLIT; ++s2) o += pO[((size_t)s2 * BN_ + row) * D_ + d] * sc[r][h][s2];
    cc[row * CCLD + d] = f2b(o);
  }
  if (t < QR * 3) {
    int r = t / 3, c = t % 3;
    size_t row = i0 + r;
    float F = 0.f;
#pragma unroll
    for (int s2 = 0; s2 < NSPLIT; ++s2) F += pF[((size_t)s2 * BN_ + row) * 3 + c] * scg[r][s2];
    cc[row * CCLD + 384 + c] = f2b(F);
  }
  for (int idx = t; idx < QR * (CCLD - 387); idx += 256) {
    int r = idx / (CCLD - 387), col = 387 + idx % (CCLD - 387);
    cc[(size_t)(i0 + r) * CCLD + col] = 0;
  }
}

// ---------------------------------------------------------------- launch
extern "C" void kernel_launch(void* const* d_in, const int* in_sizes, int n_in,
                              void* d_out, int out_size, void* d_ws, size_t ws_size,
                              hipStream_t stream) {
  const float* x_rigid = (const float*)d_in[0];
  const float* ad      = (const float*)d_in[1];
  const float* ori     = (const float*)d_in[2];
  const float* dist    = (const float*)d_in[3];
  const int*   mask    = (const int*)d_in[4];
  const float* Wq  = (const float*)d_in[5];
  const float* bq  = (const float*)d_in[6];
  const float* Wk  = (const float*)d_in[7];
  const float* bk  = (const float*)d_in[8];
  const float* Wv  = (const float*)d_in[9];
  const float* bv  = (const float*)d_in[10];
  const float* W3  = (const float*)d_in[11];
  const float* b3  = (const float*)d_in[12];
  const float* Wmlp = (const float*)d_in[13];
  const float* bmlp = (const float*)d_in[14];
  const float* Wfc  = (const float*)d_in[15];
  const float* bfc  = (const float*)d_in[16];
  const float* Wff1 = (const float*)d_in[17];
  const float* bff1 = (const float*)d_in[18];
  const float* Wff2 = (const float*)d_in[19];
  const float* bff2 = (const float*)d_in[20];
  const float* ln1g = (const float*)d_in[21];
  const float* ln1b = (const float*)d_in[22];
  const float* ln2g = (const float*)d_in[23];
  const float* ln2b = (const float*)d_in[24];

  float* x = (float*)d_out;

  size_t off = 0;
  auto alloc = [&](size_t bytes) -> void* {
    void* r = (char*)d_ws + off;
    off = (off + bytes + 255) & ~(size_t)255;
    return r;
  };
  unsigned short* WqkvT = (unsigned short*)alloc((size_t)L_ * 1152 * D_ * 2);
  unsigned short* WfcT  = (unsigned short*)alloc((size_t)L_ * D_ * CCLD * 2);
  unsigned short* Wff1T = (unsigned short*)alloc((size_t)L_ * DFF2 * D_ * 2);
  unsigned short* Wff2T = (unsigned short*)alloc((size_t)L_ * D_ * DFF2 * 2);
  float* bqkv = (float*)alloc((size_t)L_ * 1152 * 4);
  unsigned short* qp  = (unsigned short*)alloc((size_t)BN_ * 512 * 2);
  unsigned short* kp  = (unsigned short*)alloc((size_t)BN_ * 512 * 2);
  unsigned short* vTb = (unsigned short*)alloc((size_t)BN_ * D_ * 2);
  unsigned short* hb  = (unsigned short*)alloc((size_t)BN_ * D_ * 2);
  unsigned short* h2  = (unsigned short*)alloc((size_t)BN_ * D_ * 2);
  unsigned short* cc  = (unsigned short*)alloc((size_t)BN_ * CCLD * 2);
  unsigned short* ffb = (unsigned short*)alloc((size_t)BN_ * DFF2 * 2);
  float* v3 = (float*)alloc((size_t)BN_ * 3 * 4);
  float* pO = (float*)alloc((size_t)NSPLIT * BN_ * D_ * 4);
  float* pM = (float*)alloc((size_t)NSPLIT * BN_ * H_ * 4);
  float* pL = (float*)alloc((size_t)NSPLIT * BN_ * H_ * 4);
  float* pF = (float*)alloc((size_t)NSPLIT * BN_ * 3 * 4);
  float* pMg = (float*)alloc((size_t)NSPLIT * BN_ * 4);
  float* pLg = (float*)alloc((size_t)NSPLIT * BN_ * 4);
  size_t off_core = off;
  // dbias: try 4-layer variant, else single-layer
  float* db4 = (float*)alloc((size_t)L_ * BNNc * 4);
  bool use4 = (off <= ws_size);
  float* db1 = nullptr;
  if (!use4) {
    off = off_core;
    db1 = (float*)alloc(BNNc * 4);
  }
  size_t need_base = off;
  float* G = (float*)alloc(BNNc * 6 * 4);
  bool useG = (off <= ws_size);
  if (ws_size < need_base) return;  // insufficient scratch

  pack_qkv_kernel<<<(L_ * 1152 * D_ + 255) / 256, 256, 0, stream>>>(Wq, Wk, Wv, WqkvT);
  pack_bias_kernel<<<(L_ * 1152 + 255) / 256, 256, 0, stream>>>(bq, bk, bv, bqkv);
  pack_fc_kernel<<<(L_ * D_ * CCLD + 255) / 256, 256, 0, stream>>>(Wfc, WfcT);
  pack_ff1_kernel<<<(L_ * DFF2 * D_ + 255) / 256, 256, 0, stream>>>(Wff1, Wff1T);
  pack_ff2_kernel<<<(L_ * D_ * DFF2 + 255) / 256, 256, 0, stream>>>(Wff2, Wff2T);
  if (useG) geom_kernel<<<4096, 256, 0, stream>>>(ori, ad, G);
  if (use4) rbf4_kernel<<<4096, 256, 0, stream>>>(dist, mask, Wmlp, bmlp, db4);
  copy_kernel<<<(BN_ * D_) / 256, 256, 0, stream>>>(x, x_rigid, BN_ * D_);
  zero_kernel<<<(BN_ * 512 / 2 + 255) / 256, 256, 0, stream>>>((unsigned int*)qp, BN_ * 512 / 2);
  zero_kernel<<<(BN_ * 512 / 2 + 255) / 256, 256, 0, stream>>>((unsigned int*)kp, BN_ * 512 / 2);

  for (int l = 0; l < L_; ++l) {
    const float* db_l = use4 ? (db4 + (size_t)l * BNNc) : db1;
    if (!use4) rbf_kernel<<<4096, 256, 0, stream>>>(dist, mask, Wmlp + l * 16, bmlp + l, db1);
    ln_kernel<<<BN_ / 4, 256, 0, stream>>>(x, ln1g + l * D_, ln1b + l * D_, hb);
    mfma_gemm<64, 0><<<dim3(18, 32), 256, 0, stream>>>(
        hb, D_, WqkvT + (size_t)l * 1152 * D_, D_, bqkv + l * 1152,
        (float*)qp, (float*)kp, (float*)vTb, 0, D_);
    v3d_kernel<<<BN_ / 4, 256, 0, stream>>>(hb, W3 + (size_t)l * D_ * 3, b3 + l * 3, v3);
    if (useG)
      attn16_kernel<true><<<dim3(BN_ / 16, NSPLIT), 256, 0, stream>>>(
          qp, kp, vTb, db_l, G, ad, ori, v3, pO, pM, pL, pF, pMg, pLg);
    else
      attn16_kernel<false><<<dim3(BN_ / 16, NSPLIT), 256, 0, stream>>>(
          qp, kp, vTb, db_l, G, ad, ori, v3, pO, pM, pL, pF, pMg, pLg);
    combine_kernel<<<BN_ / QR, 256, 0, stream>>>(pO, pM, pL, pF, pMg, pLg, cc);
    mfma_gemm<32, 1><<<dim3(6, 64), 256, 0, stream>>>(
        cc, CCLD, WfcT + (size_t)l * D_ * CCLD, CCLD, bfc + l * D_, x, nullptr, nullptr, D_, CCLD);
    ln_kernel<<<BN_ / 4, 256, 0, stream>>>(x, ln2g + l * D_, ln2b + l * D_, h2);
    mfma_gemm<64, 2><<<dim3(8, 32), 256, 0, stream>>>(
        h2, D_, Wff1T + (size_t)l * DFF2 * D_, D_, bff1 + l * DFF2, (float*)ffb, nullptr, nullptr,
        DFF2, D_);
    mfma_gemm<32, 1><<<dim3(6, 64), 256, 0, stream>>>(
        ffb, DFF2, Wff2T + (size_t)l * D_ * DFF2, DFF2, bff2 + l * D_, x, nullptr, nullptr, D_,
        DFF2);
  }
}